// Round 2
// baseline (557.343 us; speedup 1.0000x reference)
//
#include <hip/hip_runtime.h>
#include <hip/hip_bf16.h>

#define BB 128
#define NN 512
#define IND 128
#define LD 64
#define NC 10
#define FL 4
#define ROWS (BB*NN)          // 65536

// workspace layout (float units)
#define OFF_RDEG 0
#define OFF_HWT  (OFF_RDEG + ROWS)            // hwT bf16 [B][64][512] = ROWS*32 floats
#define OFF_H    (OFF_HWT + ROWS*32)          // h f32 [B,N,64]
#define OFF_HM   (OFF_H + ROWS*64)            // hm_s [B,N]
#define OFF_HV   (OFF_HM + ROWS)
#define OFF_ZS   (OFF_HV + ROWS)
#define OFF_ZSS  (OFF_ZS + ROWS)
#define OFF_ACC  (OFF_ZSS + ROWS)             // [kl, mse, nll, acc]

typedef __attribute__((ext_vector_type(8))) short short8v;
typedef __attribute__((ext_vector_type(4))) float f32x4;

__device__ inline float wave_reduce(float v) {
    #pragma unroll
    for (int m = 32; m; m >>= 1) v += __shfl_xor(v, m, 64);
    return v;
}

__device__ inline short f2bf(float f) {
    unsigned u = __float_as_uint(f);
    u += 0x7fff + ((u >> 16) & 1);      // round-to-nearest-even
    return (short)(u >> 16);
}

// K1: deg row sums -> rdeg; also zero the scalar accumulators
__global__ void k_deg(const float* __restrict__ gs, float* __restrict__ rdeg,
                      float* __restrict__ accums) {
    if (blockIdx.x == 0 && threadIdx.x < 4) accums[threadIdx.x] = 0.f;
    int gid = blockIdx.x * blockDim.x + threadIdx.x;
    int row = gid >> 6, lane = gid & 63;
    const float4* r4 = (const float4*)(gs + (size_t)row * NN);
    float4 a = r4[lane], b = r4[lane + 64];
    float s = a.x + a.y + a.z + a.w + b.x + b.y + b.z + b.w;
    s = wave_reduce(s);
    if (lane == 0) rdeg[row] = 1.0f / s;
}

// K2: hwT[b][l][n] = bf16( rdeg[b,n] * sum_f hs[b,n,f] * W_s[f,l] )
__global__ __launch_bounds__(256) void k_hw(const float* __restrict__ hs,
                                            const float* __restrict__ W_s,
                                            const float* __restrict__ rdeg,
                                            unsigned short* __restrict__ hwT) {
    __shared__ float sW[IND * LD];       // 32 KB
    __shared__ float shs[16 * 132];      // 16 rows padded
    __shared__ unsigned short sT[64][24];
    int t = threadIdx.x;
    for (int i = t; i < IND * LD; i += 256) sW[i] = W_s[i];
    int row0 = blockIdx.x * 16;
    for (int i = t; i < 16 * IND; i += 256)
        shs[(i >> 7) * 132 + (i & 127)] = hs[(size_t)row0 * IND + i];
    __syncthreads();
    int l = t & 63, rg = t >> 6;
    float acc[4] = {0.f, 0.f, 0.f, 0.f};
    for (int f = 0; f < IND; ++f) {
        float w = sW[f * LD + l];
        #pragma unroll
        for (int r = 0; r < 4; ++r)
            acc[r] += shs[(rg * 4 + r) * 132 + f] * w;
    }
    #pragma unroll
    for (int r = 0; r < 4; ++r) {
        int row = row0 + rg * 4 + r;
        sT[l][rg * 4 + r] = (unsigned short)f2bf(acc[r] * rdeg[row]);
    }
    __syncthreads();
    if (t < 64) {
        int b = row0 >> 9, n0 = row0 & 511;
        unsigned short* dst = hwT + ((size_t)b * 64 + t) * 512 + n0;
        short8v v0, v1;
        #pragma unroll
        for (int e = 0; e < 8; ++e) { v0[e] = (short)sT[t][e]; v1[e] = (short)sT[t][8 + e]; }
        *(short8v*)dst = v0;
        *(short8v*)(dst + 8) = v1;
    }
}

// K3: h = relu(g @ hw + b_s) via bf16 MFMA. A = gs (cvt in-reg), B = hwT (bf16).
__global__ __launch_bounds__(256) void k_gemm_h(const float* __restrict__ gs,
                                                const unsigned short* __restrict__ hwT,
                                                const float* __restrict__ b_s,
                                                float* __restrict__ h) {
    int b = blockIdx.y, m0 = blockIdx.x * 64;
    int w = threadIdx.x >> 6, lane = threadIdx.x & 63;
    int mrow = m0 + w * 16 + (lane & 15);
    int koff = (lane >> 4) * 8;
    const float* A = gs + ((size_t)b * NN + mrow) * NN + koff;
    const unsigned short* Bp = hwT + ((size_t)b * 64 + (lane & 15)) * 512 + koff;
    f32x4 acc0 = {0.f,0.f,0.f,0.f}, acc1 = acc0, acc2 = acc0, acc3 = acc0;
    #pragma unroll 4
    for (int k0 = 0; k0 < NN; k0 += 32) {
        float4 af0 = *(const float4*)(A + k0);
        float4 af1 = *(const float4*)(A + k0 + 4);
        short8v a;
        a[0] = f2bf(af0.x); a[1] = f2bf(af0.y); a[2] = f2bf(af0.z); a[3] = f2bf(af0.w);
        a[4] = f2bf(af1.x); a[5] = f2bf(af1.y); a[6] = f2bf(af1.z); a[7] = f2bf(af1.w);
        short8v b0 = *(const short8v*)(Bp + k0);
        short8v b1 = *(const short8v*)(Bp + 16 * 512 + k0);
        short8v b2 = *(const short8v*)(Bp + 32 * 512 + k0);
        short8v b3 = *(const short8v*)(Bp + 48 * 512 + k0);
        acc0 = __builtin_amdgcn_mfma_f32_16x16x32_bf16(a, b0, acc0, 0, 0, 0);
        acc1 = __builtin_amdgcn_mfma_f32_16x16x32_bf16(a, b1, acc1, 0, 0, 0);
        acc2 = __builtin_amdgcn_mfma_f32_16x16x32_bf16(a, b2, acc2, 0, 0, 0);
        acc3 = __builtin_amdgcn_mfma_f32_16x16x32_bf16(a, b3, acc3, 0, 0, 0);
    }
    int r0 = (lane >> 4) * 4, col = lane & 15;
    float* hb = h + ((size_t)b * NN + m0 + w * 16) * LD;
    #pragma unroll
    for (int r = 0; r < 4; ++r) {
        hb[(r0 + r) * LD +  0 + col] = fmaxf(acc0[r] + b_s[ 0 + col], 0.f);
        hb[(r0 + r) * LD + 16 + col] = fmaxf(acc1[r] + b_s[16 + col], 0.f);
        hb[(r0 + r) * LD + 32 + col] = fmaxf(acc2[r] + b_s[32 + col], 0.f);
        hb[(r0 + r) * LD + 48 + col] = fmaxf(acc3[r] + b_s[48 + col], 0.f);
    }
}

// K4: hm_s[b,j] = rdeg[b,j]*sum_l h[b,j,l]*W_mu[l];  hv_s likewise
__global__ void k_hmv(const float* __restrict__ h, const float* __restrict__ W_mu,
                      const float* __restrict__ W_lv, const float* __restrict__ rdeg,
                      float* __restrict__ hm_s, float* __restrict__ hv_s) {
    int gid = blockIdx.x * blockDim.x + threadIdx.x;
    int row = gid >> 6, lane = gid & 63;
    float hv = h[(size_t)row * LD + lane];
    float m = wave_reduce(hv * W_mu[lane]);
    float v = wave_reduce(hv * W_lv[lane]);
    if (lane == 0) {
        float rd = rdeg[row];
        hm_s[row] = m * rd;
        hv_s[row] = v * rd;
    }
}

// K5: mu/lv matvec over gs + flow epilogue -> zs, zs_s, atomic kl
__global__ void k_muflow(const float* __restrict__ gs, const float* __restrict__ hm_s,
                         const float* __restrict__ hv_s, const float* __restrict__ eps,
                         const float* __restrict__ b_mu, const float* __restrict__ b_lv,
                         const float* __restrict__ beta, const float* __restrict__ fw,
                         const float* __restrict__ fb, const float* __restrict__ fs,
                         const float* __restrict__ rdeg,
                         float* __restrict__ zs, float* __restrict__ zs_s,
                         float* __restrict__ accums) {
    __shared__ float skl[4];
    int t = threadIdx.x;
    int gid = blockIdx.x * blockDim.x + t;
    int row = gid >> 6, lane = t & 63, wid = t >> 6;
    int b = row >> 9;
    const float4* g4 = (const float4*)(gs + (size_t)row * NN);
    const float4* m4 = (const float4*)(hm_s + (size_t)b * NN);
    const float4* v4 = (const float4*)(hv_s + (size_t)b * NN);
    float4 ga = g4[lane], gb = g4[lane + 64];
    float4 ma = m4[lane], mb = m4[lane + 64];
    float4 va = v4[lane], vb = v4[lane + 64];
    float sm = ga.x*ma.x + ga.y*ma.y + ga.z*ma.z + ga.w*ma.w
             + gb.x*mb.x + gb.y*mb.y + gb.z*mb.z + gb.w*mb.w;
    float sv = ga.x*va.x + ga.y*va.y + ga.z*va.z + ga.w*va.w
             + gb.x*vb.x + gb.y*vb.y + gb.z*vb.z + gb.w*vb.w;
    sm = wave_reduce(sm);
    sv = wave_reduce(sv);
    if (lane == 0) {
        float mu = fmaxf(sm + b_mu[0], 0.f);
        float lv = fmaxf(sv + b_lv[0], 0.f);
        float sigma = expf(0.5f * lv);
        float z0 = eps[row] * sigma + mu;
        float z = z0, lj = 0.f;
        #pragma unroll
        for (int k = 0; k < FL; ++k) {
            float tt = tanhf(fw[k] * z + fb[k]);
            float det = 1.f + fs[k] * fw[k] * (1.f - tt * tt);
            lj += logf(fabsf(det) + 1e-7f);
            z += fs[k] * tt;
        }
        float e = (z0 - mu) / sigma;
        float logq = -0.5f * e * e - logf(2.5f * sigma);
        float logp = -0.5f * z * z - logf(2.5f);
        float kl = logq - lj - logp;
        float zv = 1.f / (1.f + expf(-beta[0] * z));
        zs[row] = zv;
        zs_s[row] = zv * rdeg[row];
        skl[wid] = kl;
    }
    __syncthreads();
    if (t == 0) atomicAdd(&accums[0], skl[0] + skl[1] + skl[2] + skl[3]);
}

// K6: d_pre matvec over gs + mse epilogue (atomic)
__global__ void k_dec(const float* __restrict__ gs, const float* __restrict__ zs_s,
                      const float* __restrict__ h, const float* __restrict__ W_dec,
                      const float* __restrict__ b_dec, float* __restrict__ accums) {
    __shared__ float sms[4];
    int t = threadIdx.x;
    int gid = blockIdx.x * blockDim.x + t;
    int row = gid >> 6, lane = t & 63, wid = t >> 6;
    int b = row >> 9;
    const float4* g4 = (const float4*)(gs + (size_t)row * NN);
    const float4* z4 = (const float4*)(zs_s + (size_t)b * NN);
    float4 ga = g4[lane], gb = g4[lane + 64];
    float4 za = z4[lane], zb = z4[lane + 64];
    float s = ga.x*za.x + ga.y*za.y + ga.z*za.z + ga.w*za.w
            + gb.x*zb.x + gb.y*zb.y + gb.z*zb.z + gb.w*zb.w;
    s = wave_reduce(s);          // all lanes hold d_pre
    float dval = fmaxf(s * W_dec[lane] + b_dec[lane], 0.f);
    float diff = h[(size_t)row * LD + lane] - dval;
    float ms = wave_reduce(diff * diff);
    if (lane == 0) sms[wid] = ms;
    __syncthreads();
    if (t == 0) atomicAdd(&accums[1], sms[0] + sms[1] + sms[2] + sms[3]);
}

// K7: hg + classifier, one block per batch sample; atomics for nll/acc
__global__ __launch_bounds__(256) void k_hg_cls(const float* __restrict__ h,
                                                const float* __restrict__ zs,
                                                const float* __restrict__ W1,
                                                const float* __restrict__ b1,
                                                const float* __restrict__ W2,
                                                const float* __restrict__ b2,
                                                const int* __restrict__ labels,
                                                float* __restrict__ accums) {
    __shared__ float red[4][64];
    __shared__ float shg[64];
    __shared__ float sx[64];
    __shared__ float slg[NC];
    int bb = blockIdx.x, t = threadIdx.x, l = t & 63, c = t >> 6;
    const float* hb = h + (size_t)bb * NN * LD;
    const float* zb = zs + (size_t)bb * NN;
    float acc = 0.f;
    for (int n = c * 128; n < c * 128 + 128; ++n)
        acc += hb[(size_t)n * LD + l] * zb[n];
    red[c][l] = acc;
    __syncthreads();
    if (c == 0) shg[l] = red[0][l] + red[1][l] + red[2][l] + red[3][l];
    __syncthreads();
    if (c == 0) {
        float a2 = b1[l];
        #pragma unroll 8
        for (int k = 0; k < LD; ++k) a2 += shg[k] * W1[k * LD + l];
        sx[l] = fmaxf(a2, 0.f);
    }
    __syncthreads();
    if (t < NC) {
        float a3 = b2[t];
        #pragma unroll 8
        for (int k = 0; k < LD; ++k) a3 += sx[k] * W2[k * NC + t];
        slg[t] = a3;
    }
    __syncthreads();
    if (t == 0) {
        float mx = slg[0]; int pred = 0;
        #pragma unroll
        for (int cc = 1; cc < NC; ++cc) if (slg[cc] > mx) { mx = slg[cc]; pred = cc; }
        float se = 0.f;
        #pragma unroll
        for (int cc = 0; cc < NC; ++cc) se += expf(slg[cc] - mx);
        int lab = labels[bb];
        float nll = -(slg[lab] - (mx + logf(se)));
        atomicAdd(&accums[2], nll);
        if (pred == lab) atomicAdd(&accums[3], 1.0f);
    }
}

// K8: combine 4 scalars -> out[2]
__global__ void k_out(const float* __restrict__ accums, float* __restrict__ out) {
    if (threadIdx.x == 0) {
        out[0] = accums[2] / (float)BB
               + accums[1] / ((float)BB * NN * LD)
               + accums[0] / ((float)BB * NN);
        out[1] = accums[3] / (float)BB;
    }
}

extern "C" void kernel_launch(void* const* d_in, const int* in_sizes, int n_in,
                              void* d_out, int out_size, void* d_ws, size_t ws_size,
                              hipStream_t stream) {
    const float* gs    = (const float*)d_in[0];
    const float* hs    = (const float*)d_in[1];
    const int*   labels= (const int*)d_in[2];
    const float* eps   = (const float*)d_in[3];
    const float* W_s   = (const float*)d_in[4];
    const float* b_s   = (const float*)d_in[5];
    const float* W_mu  = (const float*)d_in[6];
    const float* b_mu  = (const float*)d_in[7];
    const float* W_lv  = (const float*)d_in[8];
    const float* b_lv  = (const float*)d_in[9];
    const float* W_dec = (const float*)d_in[10];
    const float* b_dec = (const float*)d_in[11];
    const float* W1    = (const float*)d_in[12];
    const float* b1    = (const float*)d_in[13];
    const float* W2    = (const float*)d_in[14];
    const float* b2    = (const float*)d_in[15];
    const float* beta  = (const float*)d_in[16];
    const float* fw    = (const float*)d_in[17];
    const float* fb    = (const float*)d_in[18];
    const float* fs    = (const float*)d_in[19];

    float* ws     = (float*)d_ws;
    float* rdeg   = ws + OFF_RDEG;
    unsigned short* hwT = (unsigned short*)(ws + OFF_HWT);
    float* h      = ws + OFF_H;
    float* hm_s   = ws + OFF_HM;
    float* hv_s   = ws + OFF_HV;
    float* zs     = ws + OFF_ZS;
    float* zs_s   = ws + OFF_ZSS;
    float* accums = ws + OFF_ACC;

    k_deg<<<ROWS / 4, 256, 0, stream>>>(gs, rdeg, accums);
    k_hw<<<ROWS / 16, 256, 0, stream>>>(hs, W_s, rdeg, hwT);
    k_gemm_h<<<dim3(8, BB), 256, 0, stream>>>(gs, hwT, b_s, h);
    k_hmv<<<ROWS / 4, 256, 0, stream>>>(h, W_mu, W_lv, rdeg, hm_s, hv_s);
    k_muflow<<<ROWS / 4, 256, 0, stream>>>(gs, hm_s, hv_s, eps, b_mu, b_lv, beta,
                                           fw, fb, fs, rdeg, zs, zs_s, accums);
    k_dec<<<ROWS / 4, 256, 0, stream>>>(gs, zs_s, h, W_dec, b_dec, accums);
    k_hg_cls<<<BB, 256, 0, stream>>>(h, zs, W1, b1, W2, b2, labels, accums);
    k_out<<<1, 64, 0, stream>>>(accums, (float*)d_out);
}

// Round 3
// 164.475 us; speedup vs baseline: 3.3886x; 3.3886x over previous
//
#include <hip/hip_runtime.h>
#include <hip/hip_bf16.h>

#define BB 128
#define NN 512
#define IND 128
#define LD 64
#define NC 10
#define FL 4
#define ROWS (BB*NN)          // 65536

// workspace layout (float units)
#define OFF_RDEG 0
#define OFF_HWT  (OFF_RDEG + ROWS)            // hwT bf16 [B][64][512] = ROWS*32 floats
#define OFF_H    (OFF_HWT + ROWS*32)          // h f32 [B,N,64]
#define OFF_HM   (OFF_H + ROWS*64)
#define OFF_HV   (OFF_HM + ROWS)
#define OFF_ZS   (OFF_HV + ROWS)
#define OFF_ZSS  (OFF_ZS + ROWS)
#define OFF_KLP  (OFF_ZSS + ROWS)             // 16384
#define OFF_MSEP (OFF_KLP + 16384)            // 16384
#define OFF_ACC  (OFF_MSEP + 16384)           // 4: [kl, mse, nll, acc]
#define OFF_GSB  (OFF_ACC + 4)                // gs bf16 [ROWS][512] = ROWS*256 floats
#define WS_NEED_BIG ((size_t)(OFF_GSB + (size_t)ROWS*256) * 4)

typedef __attribute__((ext_vector_type(8))) short short8v;
typedef __attribute__((ext_vector_type(4))) float f32x4;

__device__ inline float wave_reduce(float v) {
    #pragma unroll
    for (int m = 32; m; m >>= 1) v += __shfl_xor(v, m, 64);
    return v;
}

__device__ inline short f2bf(float f) {
    unsigned u = __float_as_uint(f);
    u += 0x7fff + ((u >> 16) & 1);      // round-to-nearest-even
    return (short)(u >> 16);
}

__device__ inline float bf2f(short s) {
    return __uint_as_float(((unsigned)(unsigned short)s) << 16);
}

// K1: deg row sums -> rdeg; zero accums; optionally emit bf16 copy of gs
__global__ __launch_bounds__(256) void k_deg(const float* __restrict__ gs,
                                             float* __restrict__ rdeg,
                                             float* __restrict__ accums,
                                             unsigned short* __restrict__ gsb) {
    if (blockIdx.x == 0 && threadIdx.x < 4) accums[threadIdx.x] = 0.f;
    int t = threadIdx.x;
    int row = blockIdx.x * 4 + (t >> 6), lane = t & 63;
    const float4* r4 = (const float4*)(gs + (size_t)row * NN);
    float4 a = r4[lane * 2], b = r4[lane * 2 + 1];
    float s = a.x + a.y + a.z + a.w + b.x + b.y + b.z + b.w;
    float sr = wave_reduce(s);
    if (lane == 0) rdeg[row] = 1.0f / sr;
    if (gsb) {
        short8v v;
        v[0] = f2bf(a.x); v[1] = f2bf(a.y); v[2] = f2bf(a.z); v[3] = f2bf(a.w);
        v[4] = f2bf(b.x); v[5] = f2bf(b.y); v[6] = f2bf(b.z); v[7] = f2bf(b.w);
        *(short8v*)(gsb + (size_t)row * NN + lane * 8) = v;
    }
}

// K2: hwT[b][l][n] = bf16( rdeg[b,n] * sum_f hs[b,n,f] * W_s[f,l] )
__global__ __launch_bounds__(256) void k_hw(const float* __restrict__ hs,
                                            const float* __restrict__ W_s,
                                            const float* __restrict__ rdeg,
                                            unsigned short* __restrict__ hwT) {
    __shared__ float sW[IND * LD];       // 32 KB
    __shared__ float shs[16 * 132];      // 16 rows padded
    __shared__ unsigned short sT[64][24];
    int t = threadIdx.x;
    for (int i = t; i < IND * LD; i += 256) sW[i] = W_s[i];
    int row0 = blockIdx.x * 16;
    for (int i = t; i < 16 * IND; i += 256)
        shs[(i >> 7) * 132 + (i & 127)] = hs[(size_t)row0 * IND + i];
    __syncthreads();
    int l = t & 63, rg = t >> 6;
    float acc[4] = {0.f, 0.f, 0.f, 0.f};
    for (int f = 0; f < IND; ++f) {
        float w = sW[f * LD + l];
        #pragma unroll
        for (int r = 0; r < 4; ++r)
            acc[r] += shs[(rg * 4 + r) * 132 + f] * w;
    }
    #pragma unroll
    for (int r = 0; r < 4; ++r) {
        int row = row0 + rg * 4 + r;
        sT[l][rg * 4 + r] = (unsigned short)f2bf(acc[r] * rdeg[row]);
    }
    __syncthreads();
    if (t < 64) {
        int b = row0 >> 9, n0 = row0 & 511;
        unsigned short* dst = hwT + ((size_t)b * 64 + t) * 512 + n0;
        short8v v0, v1;
        #pragma unroll
        for (int e = 0; e < 8; ++e) { v0[e] = (short)sT[t][e]; v1[e] = (short)sT[t][8 + e]; }
        *(short8v*)dst = v0;
        *(short8v*)(dst + 8) = v1;
    }
}

// K3: h = relu(g @ hw + b_s) via bf16 MFMA; fused hm_s/hv_s epilogue
template<bool BF>
__global__ __launch_bounds__(256) void k_gemm_h(const float* __restrict__ gs,
                                                const unsigned short* __restrict__ gsb,
                                                const unsigned short* __restrict__ hwT,
                                                const float* __restrict__ b_s,
                                                const float* __restrict__ W_mu,
                                                const float* __restrict__ W_lv,
                                                const float* __restrict__ rdeg,
                                                float* __restrict__ h,
                                                float* __restrict__ hm_s,
                                                float* __restrict__ hv_s) {
    int b = blockIdx.y, m0 = blockIdx.x * 64;
    int w = threadIdx.x >> 6, lane = threadIdx.x & 63;
    int mrow = m0 + w * 16 + (lane & 15);
    int koff = (lane >> 4) * 8;
    const float* A32 = gs + ((size_t)b * NN + mrow) * NN + koff;
    const unsigned short* A16 = gsb + ((size_t)b * NN + mrow) * NN + koff;
    const unsigned short* Bp = hwT + ((size_t)b * 64 + (lane & 15)) * 512 + koff;
    f32x4 acc0 = {0.f,0.f,0.f,0.f}, acc1 = acc0, acc2 = acc0, acc3 = acc0;
    #pragma unroll 4
    for (int k0 = 0; k0 < NN; k0 += 32) {
        short8v a;
        if constexpr (BF) {
            a = *(const short8v*)(A16 + k0);
        } else {
            float4 af0 = *(const float4*)(A32 + k0);
            float4 af1 = *(const float4*)(A32 + k0 + 4);
            a[0] = f2bf(af0.x); a[1] = f2bf(af0.y); a[2] = f2bf(af0.z); a[3] = f2bf(af0.w);
            a[4] = f2bf(af1.x); a[5] = f2bf(af1.y); a[6] = f2bf(af1.z); a[7] = f2bf(af1.w);
        }
        short8v b0 = *(const short8v*)(Bp + k0);
        short8v b1 = *(const short8v*)(Bp + 16 * 512 + k0);
        short8v b2 = *(const short8v*)(Bp + 32 * 512 + k0);
        short8v b3 = *(const short8v*)(Bp + 48 * 512 + k0);
        acc0 = __builtin_amdgcn_mfma_f32_16x16x32_bf16(a, b0, acc0, 0, 0, 0);
        acc1 = __builtin_amdgcn_mfma_f32_16x16x32_bf16(a, b1, acc1, 0, 0, 0);
        acc2 = __builtin_amdgcn_mfma_f32_16x16x32_bf16(a, b2, acc2, 0, 0, 0);
        acc3 = __builtin_amdgcn_mfma_f32_16x16x32_bf16(a, b3, acc3, 0, 0, 0);
    }
    int r0 = (lane >> 4) * 4, col = lane & 15;
    float* hb = h + ((size_t)b * NN + m0 + w * 16) * LD;
    float bs0 = b_s[col], bs1 = b_s[16 + col], bs2 = b_s[32 + col], bs3 = b_s[48 + col];
    float wm0 = W_mu[col], wm1 = W_mu[16 + col], wm2 = W_mu[32 + col], wm3 = W_mu[48 + col];
    float wv0 = W_lv[col], wv1 = W_lv[16 + col], wv2 = W_lv[32 + col], wv3 = W_lv[48 + col];
    #pragma unroll
    for (int r = 0; r < 4; ++r) {
        float h0 = fmaxf(acc0[r] + bs0, 0.f);
        float h1 = fmaxf(acc1[r] + bs1, 0.f);
        float h2 = fmaxf(acc2[r] + bs2, 0.f);
        float h3 = fmaxf(acc3[r] + bs3, 0.f);
        hb[(r0 + r) * LD +  0 + col] = h0;
        hb[(r0 + r) * LD + 16 + col] = h1;
        hb[(r0 + r) * LD + 32 + col] = h2;
        hb[(r0 + r) * LD + 48 + col] = h3;
        float pm = h0 * wm0 + h1 * wm1 + h2 * wm2 + h3 * wm3;
        float pv = h0 * wv0 + h1 * wv1 + h2 * wv2 + h3 * wv3;
        #pragma unroll
        for (int mk = 8; mk; mk >>= 1) {
            pm += __shfl_xor(pm, mk, 64);
            pv += __shfl_xor(pv, mk, 64);
        }
        if (col == 0) {
            int grow = b * NN + m0 + w * 16 + r0 + r;
            float rd = rdeg[grow];
            hm_s[grow] = pm * rd;
            hv_s[grow] = pv * rd;
        }
    }
}

// K5: mu/lv matvec over g + flow epilogue -> zs, zs_s, klp[block]
template<bool BF>
__global__ __launch_bounds__(256) void k_muflow(const float* __restrict__ gs,
                         const unsigned short* __restrict__ gsb,
                         const float* __restrict__ hm_s,
                         const float* __restrict__ hv_s, const float* __restrict__ eps,
                         const float* __restrict__ b_mu, const float* __restrict__ b_lv,
                         const float* __restrict__ beta, const float* __restrict__ fw,
                         const float* __restrict__ fb, const float* __restrict__ fs,
                         const float* __restrict__ rdeg,
                         float* __restrict__ zs, float* __restrict__ zs_s,
                         float* __restrict__ klp) {
    __shared__ float skl[4];
    int t = threadIdx.x, lane = t & 63, wid = t >> 6;
    int row = blockIdx.x * 4 + wid;
    int b = row >> 9;
    float sm, sv;
    if constexpr (BF) {
        short8v g8 = *(const short8v*)(gsb + (size_t)row * NN + lane * 8);
        const float4* m4 = (const float4*)(hm_s + (size_t)b * NN + lane * 8);
        const float4* v4 = (const float4*)(hv_s + (size_t)b * NN + lane * 8);
        float4 ma = m4[0], mb = m4[1], va = v4[0], vb = v4[1];
        float g0 = bf2f(g8[0]), g1 = bf2f(g8[1]), g2 = bf2f(g8[2]), g3 = bf2f(g8[3]);
        float g4 = bf2f(g8[4]), g5 = bf2f(g8[5]), g6 = bf2f(g8[6]), g7 = bf2f(g8[7]);
        sm = g0*ma.x + g1*ma.y + g2*ma.z + g3*ma.w + g4*mb.x + g5*mb.y + g6*mb.z + g7*mb.w;
        sv = g0*va.x + g1*va.y + g2*va.z + g3*va.w + g4*vb.x + g5*vb.y + g6*vb.z + g7*vb.w;
    } else {
        const float4* g4p = (const float4*)(gs + (size_t)row * NN);
        const float4* m4 = (const float4*)(hm_s + (size_t)b * NN);
        const float4* v4 = (const float4*)(hv_s + (size_t)b * NN);
        float4 ga = g4p[lane], gb = g4p[lane + 64];
        float4 ma = m4[lane], mb = m4[lane + 64];
        float4 va = v4[lane], vb = v4[lane + 64];
        sm = ga.x*ma.x + ga.y*ma.y + ga.z*ma.z + ga.w*ma.w
           + gb.x*mb.x + gb.y*mb.y + gb.z*mb.z + gb.w*mb.w;
        sv = ga.x*va.x + ga.y*va.y + ga.z*va.z + ga.w*va.w
           + gb.x*vb.x + gb.y*vb.y + gb.z*vb.z + gb.w*vb.w;
    }
    sm = wave_reduce(sm);
    sv = wave_reduce(sv);
    if (lane == 0) {
        float mu = fmaxf(sm + b_mu[0], 0.f);
        float lv = fmaxf(sv + b_lv[0], 0.f);
        float sigma = expf(0.5f * lv);
        float z0 = eps[row] * sigma + mu;
        float z = z0, lj = 0.f;
        #pragma unroll
        for (int k = 0; k < FL; ++k) {
            float tt = tanhf(fw[k] * z + fb[k]);
            float det = 1.f + fs[k] * fw[k] * (1.f - tt * tt);
            lj += logf(fabsf(det) + 1e-7f);
            z += fs[k] * tt;
        }
        float e = (z0 - mu) / sigma;
        float logq = -0.5f * e * e - logf(2.5f * sigma);
        float logp = -0.5f * z * z - logf(2.5f);
        float kl = logq - lj - logp;
        float zv = 1.f / (1.f + expf(-beta[0] * z));
        zs[row] = zv;
        zs_s[row] = zv * rdeg[row];
        skl[wid] = kl;
    }
    __syncthreads();
    if (t == 0) klp[blockIdx.x] = skl[0] + skl[1] + skl[2] + skl[3];
}

// K6: d_pre matvec over g + mse epilogue -> msep[block]
template<bool BF>
__global__ __launch_bounds__(256) void k_dec(const float* __restrict__ gs,
                      const unsigned short* __restrict__ gsb,
                      const float* __restrict__ zs_s,
                      const float* __restrict__ h, const float* __restrict__ W_dec,
                      const float* __restrict__ b_dec, float* __restrict__ msep) {
    __shared__ float sms[4];
    int t = threadIdx.x, lane = t & 63, wid = t >> 6;
    int row = blockIdx.x * 4 + wid;
    int b = row >> 9;
    float s;
    if constexpr (BF) {
        short8v g8 = *(const short8v*)(gsb + (size_t)row * NN + lane * 8);
        const float4* z4 = (const float4*)(zs_s + (size_t)b * NN + lane * 8);
        float4 za = z4[0], zb = z4[1];
        s = bf2f(g8[0])*za.x + bf2f(g8[1])*za.y + bf2f(g8[2])*za.z + bf2f(g8[3])*za.w
          + bf2f(g8[4])*zb.x + bf2f(g8[5])*zb.y + bf2f(g8[6])*zb.z + bf2f(g8[7])*zb.w;
    } else {
        const float4* g4p = (const float4*)(gs + (size_t)row * NN);
        const float4* z4 = (const float4*)(zs_s + (size_t)b * NN);
        float4 ga = g4p[lane], gb = g4p[lane + 64];
        float4 za = z4[lane], zb = z4[lane + 64];
        s = ga.x*za.x + ga.y*za.y + ga.z*za.z + ga.w*za.w
          + gb.x*zb.x + gb.y*zb.y + gb.z*zb.z + gb.w*zb.w;
    }
    s = wave_reduce(s);          // all lanes hold d_pre
    float dval = fmaxf(s * W_dec[lane] + b_dec[lane], 0.f);
    float diff = h[(size_t)row * LD + lane] - dval;
    float ms = wave_reduce(diff * diff);
    if (lane == 0) sms[wid] = ms;
    __syncthreads();
    if (t == 0) msep[blockIdx.x] = sms[0] + sms[1] + sms[2] + sms[3];
}

// K7: hg + classifier + partials reduction; atomics (few) into accums
__global__ __launch_bounds__(256) void k_hg_cls(const float* __restrict__ h,
                                                const float* __restrict__ zs,
                                                const float* __restrict__ W1,
                                                const float* __restrict__ b1,
                                                const float* __restrict__ W2,
                                                const float* __restrict__ b2,
                                                const int* __restrict__ labels,
                                                const float* __restrict__ klp,
                                                const float* __restrict__ msep,
                                                float* __restrict__ accums) {
    __shared__ float red[4][64];
    __shared__ float shg[64];
    __shared__ float sx[64];
    __shared__ float slg[NC];
    int bb = blockIdx.x, t = threadIdx.x, l = t & 63, c = t >> 6;
    // reduce this block's 128-slices of klp and msep (arrays are 16384 = 128*128)
    {
        float pv;
        if (c == 0)      pv = klp[bb * 128 + l];
        else if (c == 1) pv = klp[bb * 128 + 64 + l];
        else if (c == 2) pv = msep[bb * 128 + l];
        else             pv = msep[bb * 128 + 64 + l];
        pv = wave_reduce(pv);
        if (l == 0) atomicAdd(&accums[(c < 2) ? 0 : 1], pv);
    }
    const float* hb = h + (size_t)bb * NN * LD;
    const float* zb = zs + (size_t)bb * NN;
    float acc = 0.f;
    for (int n = c * 128; n < c * 128 + 128; ++n)
        acc += hb[(size_t)n * LD + l] * zb[n];
    red[c][l] = acc;
    __syncthreads();
    if (c == 0) shg[l] = red[0][l] + red[1][l] + red[2][l] + red[3][l];
    __syncthreads();
    if (c == 0) {
        float a2 = b1[l];
        #pragma unroll 8
        for (int k = 0; k < LD; ++k) a2 += shg[k] * W1[k * LD + l];
        sx[l] = fmaxf(a2, 0.f);
    }
    __syncthreads();
    if (t < NC) {
        float a3 = b2[t];
        #pragma unroll 8
        for (int k = 0; k < LD; ++k) a3 += sx[k] * W2[k * NC + t];
        slg[t] = a3;
    }
    __syncthreads();
    if (t == 0) {
        float mx = slg[0]; int pred = 0;
        #pragma unroll
        for (int cc = 1; cc < NC; ++cc) if (slg[cc] > mx) { mx = slg[cc]; pred = cc; }
        float se = 0.f;
        #pragma unroll
        for (int cc = 0; cc < NC; ++cc) se += expf(slg[cc] - mx);
        int lab = labels[bb];
        float nll = -(slg[lab] - (mx + logf(se)));
        atomicAdd(&accums[2], nll);
        if (pred == lab) atomicAdd(&accums[3], 1.0f);
    }
}

// K8: combine 4 scalars -> out[2]
__global__ void k_out(const float* __restrict__ accums, float* __restrict__ out) {
    if (threadIdx.x == 0) {
        out[0] = accums[2] / (float)BB
               + accums[1] / ((float)BB * NN * LD)
               + accums[0] / ((float)BB * NN);
        out[1] = accums[3] / (float)BB;
    }
}

extern "C" void kernel_launch(void* const* d_in, const int* in_sizes, int n_in,
                              void* d_out, int out_size, void* d_ws, size_t ws_size,
                              hipStream_t stream) {
    const float* gs    = (const float*)d_in[0];
    const float* hs    = (const float*)d_in[1];
    const int*   labels= (const int*)d_in[2];
    const float* eps   = (const float*)d_in[3];
    const float* W_s   = (const float*)d_in[4];
    const float* b_s   = (const float*)d_in[5];
    const float* W_mu  = (const float*)d_in[6];
    const float* b_mu  = (const float*)d_in[7];
    const float* W_lv  = (const float*)d_in[8];
    const float* b_lv  = (const float*)d_in[9];
    const float* W_dec = (const float*)d_in[10];
    const float* b_dec = (const float*)d_in[11];
    const float* W1    = (const float*)d_in[12];
    const float* b1    = (const float*)d_in[13];
    const float* W2    = (const float*)d_in[14];
    const float* b2    = (const float*)d_in[15];
    const float* beta  = (const float*)d_in[16];
    const float* fw    = (const float*)d_in[17];
    const float* fb    = (const float*)d_in[18];
    const float* fs    = (const float*)d_in[19];

    float* ws     = (float*)d_ws;
    float* rdeg   = ws + OFF_RDEG;
    unsigned short* hwT = (unsigned short*)(ws + OFF_HWT);
    float* h      = ws + OFF_H;
    float* hm_s   = ws + OFF_HM;
    float* hv_s   = ws + OFF_HV;
    float* zs     = ws + OFF_ZS;
    float* zs_s   = ws + OFF_ZSS;
    float* klp    = ws + OFF_KLP;
    float* msep   = ws + OFF_MSEP;
    float* accums = ws + OFF_ACC;
    unsigned short* gsb = (unsigned short*)(ws + OFF_GSB);

    bool big = ws_size >= WS_NEED_BIG;

    k_deg<<<ROWS / 4, 256, 0, stream>>>(gs, rdeg, accums, big ? gsb : nullptr);
    k_hw<<<ROWS / 16, 256, 0, stream>>>(hs, W_s, rdeg, hwT);
    if (big) {
        k_gemm_h<true><<<dim3(8, BB), 256, 0, stream>>>(gs, gsb, hwT, b_s, W_mu, W_lv,
                                                        rdeg, h, hm_s, hv_s);
        k_muflow<true><<<ROWS / 4, 256, 0, stream>>>(gs, gsb, hm_s, hv_s, eps, b_mu, b_lv,
                                                     beta, fw, fb, fs, rdeg, zs, zs_s, klp);
        k_dec<true><<<ROWS / 4, 256, 0, stream>>>(gs, gsb, zs_s, h, W_dec, b_dec, msep);
    } else {
        k_gemm_h<false><<<dim3(8, BB), 256, 0, stream>>>(gs, gsb, hwT, b_s, W_mu, W_lv,
                                                         rdeg, h, hm_s, hv_s);
        k_muflow<false><<<ROWS / 4, 256, 0, stream>>>(gs, gsb, hm_s, hv_s, eps, b_mu, b_lv,
                                                      beta, fw, fb, fs, rdeg, zs, zs_s, klp);
        k_dec<false><<<ROWS / 4, 256, 0, stream>>>(gs, gsb, zs_s, h, W_dec, b_dec, msep);
    }
    k_hg_cls<<<BB, 256, 0, stream>>>(h, zs, W1, b1, W2, b2, labels, klp, msep, accums);
    k_out<<<1, 64, 0, stream>>>(accums, (float*)d_out);
}

// Round 4
// 154.070 us; speedup vs baseline: 3.6175x; 1.0675x over previous
//
#include <hip/hip_runtime.h>
#include <hip/hip_bf16.h>

#define BB 128
#define NN 512
#define IND 128
#define LD 64
#define NC 10
#define FL 4
#define ROWS (BB*NN)          // 65536

// workspace layout (float units)
#define OFF_RDEG 0
#define OFF_HWT  (OFF_RDEG + ROWS)            // hwT bf16 [B][64][512] = ROWS*32 floats
#define OFF_H    (OFF_HWT + ROWS*32)          // h bf16 [B,N,64]      = ROWS*32 floats
#define OFF_HM   (OFF_H + ROWS*32)
#define OFF_HV   (OFF_HM + ROWS)
#define OFF_ZS   (OFF_HV + ROWS)
#define OFF_ZSS  (OFF_ZS + ROWS)
#define OFF_KLP  (OFF_ZSS + ROWS)             // 4096
#define OFF_MSEP (OFF_KLP + 4096)             // 4096
#define OFF_ACC  (OFF_MSEP + 4096)            // 8: [kl, mse, nll, acc, counter, ...]
#define OFF_GSB  (OFF_ACC + 8)                // gs bf16 [ROWS][512] = ROWS*256 floats
#define WS_NEED_BIG ((size_t)(OFF_GSB + (size_t)ROWS*256) * 4)

typedef __attribute__((ext_vector_type(8))) short short8v;
typedef __attribute__((ext_vector_type(4))) float f32x4;

__device__ inline float wave_reduce(float v) {
    #pragma unroll
    for (int m = 32; m; m >>= 1) v += __shfl_xor(v, m, 64);
    return v;
}

__device__ inline short f2bf(float f) {
    unsigned u = __float_as_uint(f);
    u += 0x7fff + ((u >> 16) & 1);      // round-to-nearest-even
    return (short)(u >> 16);
}

__device__ inline float bf2f(short s) {
    return __uint_as_float(((unsigned)(unsigned short)s) << 16);
}

// K1: deg row sums -> rdeg; zero accums; emit bf16 copy of gs
__global__ __launch_bounds__(256) void k_deg(const float* __restrict__ gs,
                                             float* __restrict__ rdeg,
                                             float* __restrict__ accums,
                                             unsigned short* __restrict__ gsb) {
    if (blockIdx.x == 0 && threadIdx.x < 8) accums[threadIdx.x] = 0.f;
    int t = threadIdx.x;
    int row = blockIdx.x * 4 + (t >> 6), lane = t & 63;
    const float4* r4 = (const float4*)(gs + (size_t)row * NN);
    float4 a = r4[lane * 2], b = r4[lane * 2 + 1];
    float s = a.x + a.y + a.z + a.w + b.x + b.y + b.z + b.w;
    float sr = wave_reduce(s);
    if (lane == 0) rdeg[row] = 1.0f / sr;
    if (gsb) {
        short8v v;
        v[0] = f2bf(a.x); v[1] = f2bf(a.y); v[2] = f2bf(a.z); v[3] = f2bf(a.w);
        v[4] = f2bf(b.x); v[5] = f2bf(b.y); v[6] = f2bf(b.z); v[7] = f2bf(b.w);
        *(short8v*)(gsb + (size_t)row * NN + lane * 8) = v;
    }
}

// K2: hwT[b][l][n] = bf16( rdeg[b,n] * sum_f hs[b,n,f] * W_s[f,l] )
__global__ __launch_bounds__(256) void k_hw(const float* __restrict__ hs,
                                            const float* __restrict__ W_s,
                                            const float* __restrict__ rdeg,
                                            unsigned short* __restrict__ hwT) {
    __shared__ float sW[IND * LD];       // 32 KB
    __shared__ float shs[16 * 132];      // 16 rows padded
    __shared__ unsigned short sT[64][24];
    int t = threadIdx.x;
    for (int i = t; i < IND * LD; i += 256) sW[i] = W_s[i];
    int row0 = blockIdx.x * 16;
    for (int i = t; i < 16 * IND; i += 256)
        shs[(i >> 7) * 132 + (i & 127)] = hs[(size_t)row0 * IND + i];
    __syncthreads();
    int l = t & 63, rg = t >> 6;
    float acc[4] = {0.f, 0.f, 0.f, 0.f};
    for (int f = 0; f < IND; ++f) {
        float w = sW[f * LD + l];
        #pragma unroll
        for (int r = 0; r < 4; ++r)
            acc[r] += shs[(rg * 4 + r) * 132 + f] * w;
    }
    #pragma unroll
    for (int r = 0; r < 4; ++r) {
        int row = row0 + rg * 4 + r;
        sT[l][rg * 4 + r] = (unsigned short)f2bf(acc[r] * rdeg[row]);
    }
    __syncthreads();
    if (t < 64) {
        int b = row0 >> 9, n0 = row0 & 511;
        unsigned short* dst = hwT + ((size_t)b * 64 + t) * 512 + n0;
        short8v v0, v1;
        #pragma unroll
        for (int e = 0; e < 8; ++e) { v0[e] = (short)sT[t][e]; v1[e] = (short)sT[t][8 + e]; }
        *(short8v*)dst = v0;
        *(short8v*)(dst + 8) = v1;
    }
}

// K3: h = relu(g @ hw + b_s) via bf16 MFMA; M-tile 128 (512 thr, 8 waves);
// fused hm_s/hv_s epilogue; bf16 h output.
template<bool BF>
__global__ __launch_bounds__(512) void k_gemm_h(const float* __restrict__ gs,
                                                const unsigned short* __restrict__ gsb,
                                                const unsigned short* __restrict__ hwT,
                                                const float* __restrict__ b_s,
                                                const float* __restrict__ W_mu,
                                                const float* __restrict__ W_lv,
                                                const float* __restrict__ rdeg,
                                                unsigned short* __restrict__ h,
                                                float* __restrict__ hm_s,
                                                float* __restrict__ hv_s) {
    int b = blockIdx.y, m0 = blockIdx.x * 128;
    int w = threadIdx.x >> 6, lane = threadIdx.x & 63;
    int mrow = m0 + w * 16 + (lane & 15);
    int koff = (lane >> 4) * 8;
    const float* A32 = gs + ((size_t)b * NN + mrow) * NN + koff;
    const unsigned short* A16 = gsb + ((size_t)b * NN + mrow) * NN + koff;
    const unsigned short* Bp = hwT + ((size_t)b * 64 + (lane & 15)) * 512 + koff;
    f32x4 acc0 = {0.f,0.f,0.f,0.f}, acc1 = acc0, acc2 = acc0, acc3 = acc0;
    #pragma unroll 4
    for (int k0 = 0; k0 < NN; k0 += 32) {
        short8v a;
        if constexpr (BF) {
            a = *(const short8v*)(A16 + k0);
        } else {
            float4 af0 = *(const float4*)(A32 + k0);
            float4 af1 = *(const float4*)(A32 + k0 + 4);
            a[0] = f2bf(af0.x); a[1] = f2bf(af0.y); a[2] = f2bf(af0.z); a[3] = f2bf(af0.w);
            a[4] = f2bf(af1.x); a[5] = f2bf(af1.y); a[6] = f2bf(af1.z); a[7] = f2bf(af1.w);
        }
        short8v b0 = *(const short8v*)(Bp + k0);
        short8v b1 = *(const short8v*)(Bp + 16 * 512 + k0);
        short8v b2 = *(const short8v*)(Bp + 32 * 512 + k0);
        short8v b3 = *(const short8v*)(Bp + 48 * 512 + k0);
        acc0 = __builtin_amdgcn_mfma_f32_16x16x32_bf16(a, b0, acc0, 0, 0, 0);
        acc1 = __builtin_amdgcn_mfma_f32_16x16x32_bf16(a, b1, acc1, 0, 0, 0);
        acc2 = __builtin_amdgcn_mfma_f32_16x16x32_bf16(a, b2, acc2, 0, 0, 0);
        acc3 = __builtin_amdgcn_mfma_f32_16x16x32_bf16(a, b3, acc3, 0, 0, 0);
    }
    int r0 = (lane >> 4) * 4, col = lane & 15;
    unsigned short* hb = h + ((size_t)b * NN + m0 + w * 16) * LD;
    float bs0 = b_s[col], bs1 = b_s[16 + col], bs2 = b_s[32 + col], bs3 = b_s[48 + col];
    float wm0 = W_mu[col], wm1 = W_mu[16 + col], wm2 = W_mu[32 + col], wm3 = W_mu[48 + col];
    float wv0 = W_lv[col], wv1 = W_lv[16 + col], wv2 = W_lv[32 + col], wv3 = W_lv[48 + col];
    #pragma unroll
    for (int r = 0; r < 4; ++r) {
        float h0 = fmaxf(acc0[r] + bs0, 0.f);
        float h1 = fmaxf(acc1[r] + bs1, 0.f);
        float h2 = fmaxf(acc2[r] + bs2, 0.f);
        float h3 = fmaxf(acc3[r] + bs3, 0.f);
        hb[(r0 + r) * LD +  0 + col] = (unsigned short)f2bf(h0);
        hb[(r0 + r) * LD + 16 + col] = (unsigned short)f2bf(h1);
        hb[(r0 + r) * LD + 32 + col] = (unsigned short)f2bf(h2);
        hb[(r0 + r) * LD + 48 + col] = (unsigned short)f2bf(h3);
        float pm = h0 * wm0 + h1 * wm1 + h2 * wm2 + h3 * wm3;
        float pv = h0 * wv0 + h1 * wv1 + h2 * wv2 + h3 * wv3;
        #pragma unroll
        for (int mk = 8; mk; mk >>= 1) {
            pm += __shfl_xor(pm, mk, 64);
            pv += __shfl_xor(pv, mk, 64);
        }
        if (col == 0) {
            int grow = b * NN + m0 + w * 16 + r0 + r;
            float rd = rdeg[grow];
            hm_s[grow] = pm * rd;
            hv_s[grow] = pv * rd;
        }
    }
}

// K5: mu/lv matvec over g + flow epilogue; 4 rows per wave, 16 rows per block.
template<bool BF>
__global__ __launch_bounds__(256) void k_muflow(const float* __restrict__ gs,
                         const unsigned short* __restrict__ gsb,
                         const float* __restrict__ hm_s,
                         const float* __restrict__ hv_s, const float* __restrict__ eps,
                         const float* __restrict__ b_mu, const float* __restrict__ b_lv,
                         const float* __restrict__ beta, const float* __restrict__ fw,
                         const float* __restrict__ fb, const float* __restrict__ fs,
                         const float* __restrict__ rdeg,
                         float* __restrict__ zs, float* __restrict__ zs_s,
                         float* __restrict__ klp) {
    __shared__ float skl[4];
    int t = threadIdx.x, lane = t & 63, wid = t >> 6;
    int base = blockIdx.x * 16 + wid * 4;      // 4 rows for this wave
    int b = base >> 9;
    // per-batch vectors loaded once per wave
    const float4* m4 = (const float4*)(hm_s + (size_t)b * NN + lane * 8);
    const float4* v4 = (const float4*)(hv_s + (size_t)b * NN + lane * 8);
    float4 ma = m4[0], mb = m4[1], va = v4[0], vb = v4[1];
    float smr[4], svr[4];
    #pragma unroll
    for (int r = 0; r < 4; ++r) {
        int row = base + r;
        float g0,g1,g2,g3,g4,g5,g6,g7;
        if constexpr (BF) {
            short8v g8 = *(const short8v*)(gsb + (size_t)row * NN + lane * 8);
            g0=bf2f(g8[0]); g1=bf2f(g8[1]); g2=bf2f(g8[2]); g3=bf2f(g8[3]);
            g4=bf2f(g8[4]); g5=bf2f(g8[5]); g6=bf2f(g8[6]); g7=bf2f(g8[7]);
        } else {
            const float4* gp = (const float4*)(gs + (size_t)row * NN + lane * 8);
            float4 ga = gp[0], gb = gp[1];
            g0=ga.x; g1=ga.y; g2=ga.z; g3=ga.w; g4=gb.x; g5=gb.y; g6=gb.z; g7=gb.w;
        }
        float sm = g0*ma.x + g1*ma.y + g2*ma.z + g3*ma.w
                 + g4*mb.x + g5*mb.y + g6*mb.z + g7*mb.w;
        float sv = g0*va.x + g1*va.y + g2*va.z + g3*va.w
                 + g4*vb.x + g5*vb.y + g6*vb.z + g7*vb.w;
        smr[r] = wave_reduce(sm);
        svr[r] = wave_reduce(sv);
    }
    // lane-parallel flow: lane handles row base + (lane&3)
    int r = lane & 3;
    float sm = (r == 0) ? smr[0] : (r == 1) ? smr[1] : (r == 2) ? smr[2] : smr[3];
    float sv = (r == 0) ? svr[0] : (r == 1) ? svr[1] : (r == 2) ? svr[2] : svr[3];
    int row = base + r;
    float mu = fmaxf(sm + b_mu[0], 0.f);
    float lv = fmaxf(sv + b_lv[0], 0.f);
    float sigma = expf(0.5f * lv);
    float z0 = eps[row] * sigma + mu;
    float z = z0, lj = 0.f;
    #pragma unroll
    for (int k = 0; k < FL; ++k) {
        float tt = tanhf(fw[k] * z + fb[k]);
        float det = 1.f + fs[k] * fw[k] * (1.f - tt * tt);
        lj += logf(fabsf(det) + 1e-7f);
        z += fs[k] * tt;
    }
    float e = (z0 - mu) / sigma;
    float logq = -0.5f * e * e - logf(2.5f * sigma);
    float logp = -0.5f * z * z - logf(2.5f);
    float kl = logq - lj - logp;
    float zv = 1.f / (1.f + expf(-beta[0] * z));
    if (lane < 4) {
        zs[row] = zv;
        zs_s[row] = zv * rdeg[row];
    }
    kl += __shfl_xor(kl, 1, 64);
    kl += __shfl_xor(kl, 2, 64);     // lane0: sum of 4 rows
    if (lane == 0) skl[wid] = kl;
    __syncthreads();
    if (t == 0) klp[blockIdx.x] = skl[0] + skl[1] + skl[2] + skl[3];
}

// K6: d_pre matvec over g + mse epilogue; 4 rows per wave, bf16 h.
template<bool BF>
__global__ __launch_bounds__(256) void k_dec(const float* __restrict__ gs,
                      const unsigned short* __restrict__ gsb,
                      const float* __restrict__ zs_s,
                      const unsigned short* __restrict__ h,
                      const float* __restrict__ W_dec,
                      const float* __restrict__ b_dec, float* __restrict__ msep) {
    __shared__ float sms[4];
    int t = threadIdx.x, lane = t & 63, wid = t >> 6;
    int base = blockIdx.x * 16 + wid * 4;
    int b = base >> 9;
    const float4* z4 = (const float4*)(zs_s + (size_t)b * NN + lane * 8);
    float4 za = z4[0], zb = z4[1];
    float wd = W_dec[lane], bd = b_dec[lane];
    float msacc = 0.f;
    #pragma unroll
    for (int r = 0; r < 4; ++r) {
        int row = base + r;
        float s;
        if constexpr (BF) {
            short8v g8 = *(const short8v*)(gsb + (size_t)row * NN + lane * 8);
            s = bf2f(g8[0])*za.x + bf2f(g8[1])*za.y + bf2f(g8[2])*za.z + bf2f(g8[3])*za.w
              + bf2f(g8[4])*zb.x + bf2f(g8[5])*zb.y + bf2f(g8[6])*zb.z + bf2f(g8[7])*zb.w;
        } else {
            const float4* gp = (const float4*)(gs + (size_t)row * NN + lane * 8);
            float4 ga = gp[0], gb = gp[1];
            s = ga.x*za.x + ga.y*za.y + ga.z*za.z + ga.w*za.w
              + gb.x*zb.x + gb.y*zb.y + gb.z*zb.z + gb.w*zb.w;
        }
        s = wave_reduce(s);
        float dval = fmaxf(s * wd + bd, 0.f);
        float diff = bf2f((short)h[(size_t)row * LD + lane]) - dval;
        msacc += diff * diff;
    }
    msacc = wave_reduce(msacc);
    if (lane == 0) sms[wid] = msacc;
    __syncthreads();
    if (t == 0) msep[blockIdx.x] = sms[0] + sms[1] + sms[2] + sms[3];
}

// K7: hg + classifier + partials reduction + last-block finalize.
__global__ __launch_bounds__(256) void k_hg_cls(const unsigned short* __restrict__ h,
                                                const float* __restrict__ zs,
                                                const float* __restrict__ W1,
                                                const float* __restrict__ b1,
                                                const float* __restrict__ W2,
                                                const float* __restrict__ b2,
                                                const int* __restrict__ labels,
                                                const float* __restrict__ klp,
                                                const float* __restrict__ msep,
                                                float* __restrict__ accums,
                                                float* __restrict__ out) {
    __shared__ float red[4][64];
    __shared__ float shg[64];
    __shared__ float sx[64];
    __shared__ float slg[NC];
    int bb = blockIdx.x, t = threadIdx.x, l = t & 63, c = t >> 6;
    // reduce this block's 32-slices of klp and msep (arrays are 4096 = 128*32)
    if (c == 0) {
        float pv = (l < 32) ? klp[bb * 32 + l] : 0.f;
        pv = wave_reduce(pv);
        if (l == 0) atomicAdd(&accums[0], pv);
    } else if (c == 1) {
        float pv = (l < 32) ? msep[bb * 32 + l] : 0.f;
        pv = wave_reduce(pv);
        if (l == 0) atomicAdd(&accums[1], pv);
    }
    const unsigned short* hb = h + (size_t)bb * NN * LD;
    const float* zb = zs + (size_t)bb * NN;
    float acc = 0.f;
    for (int n = c * 128; n < c * 128 + 128; ++n)
        acc += bf2f((short)hb[(size_t)n * LD + l]) * zb[n];
    red[c][l] = acc;
    __syncthreads();
    if (c == 0) shg[l] = red[0][l] + red[1][l] + red[2][l] + red[3][l];
    __syncthreads();
    if (c == 0) {
        float a2 = b1[l];
        #pragma unroll 8
        for (int k = 0; k < LD; ++k) a2 += shg[k] * W1[k * LD + l];
        sx[l] = fmaxf(a2, 0.f);
    }
    __syncthreads();
    if (t < NC) {
        float a3 = b2[t];
        #pragma unroll 8
        for (int k = 0; k < LD; ++k) a3 += sx[k] * W2[k * NC + t];
        slg[t] = a3;
    }
    __syncthreads();
    if (t == 0) {
        float mx = slg[0]; int pred = 0;
        #pragma unroll
        for (int cc = 1; cc < NC; ++cc) if (slg[cc] > mx) { mx = slg[cc]; pred = cc; }
        float se = 0.f;
        #pragma unroll
        for (int cc = 0; cc < NC; ++cc) se += expf(slg[cc] - mx);
        int lab = labels[bb];
        float nll = -(slg[lab] - (mx + logf(se)));
        atomicAdd(&accums[2], nll);
        if (pred == lab) atomicAdd(&accums[3], 1.0f);
        __threadfence();
        unsigned* cnt = (unsigned*)(accums + 4);
        unsigned old = atomicAdd(cnt, 1u);
        if (old == BB - 1) {
            float kk = atomicAdd(&accums[0], 0.f);
            float mm = atomicAdd(&accums[1], 0.f);
            float nn = atomicAdd(&accums[2], 0.f);
            float aa = atomicAdd(&accums[3], 0.f);
            out[0] = nn / (float)BB
                   + mm / ((float)BB * NN * LD)
                   + kk / ((float)BB * NN);
            out[1] = aa / (float)BB;
        }
    }
}

extern "C" void kernel_launch(void* const* d_in, const int* in_sizes, int n_in,
                              void* d_out, int out_size, void* d_ws, size_t ws_size,
                              hipStream_t stream) {
    const float* gs    = (const float*)d_in[0];
    const float* hs    = (const float*)d_in[1];
    const int*   labels= (const int*)d_in[2];
    const float* eps   = (const float*)d_in[3];
    const float* W_s   = (const float*)d_in[4];
    const float* b_s   = (const float*)d_in[5];
    const float* W_mu  = (const float*)d_in[6];
    const float* b_mu  = (const float*)d_in[7];
    const float* W_lv  = (const float*)d_in[8];
    const float* b_lv  = (const float*)d_in[9];
    const float* W_dec = (const float*)d_in[10];
    const float* b_dec = (const float*)d_in[11];
    const float* W1    = (const float*)d_in[12];
    const float* b1    = (const float*)d_in[13];
    const float* W2    = (const float*)d_in[14];
    const float* b2    = (const float*)d_in[15];
    const float* beta  = (const float*)d_in[16];
    const float* fw    = (const float*)d_in[17];
    const float* fb    = (const float*)d_in[18];
    const float* fs    = (const float*)d_in[19];

    float* ws     = (float*)d_ws;
    float* rdeg   = ws + OFF_RDEG;
    unsigned short* hwT = (unsigned short*)(ws + OFF_HWT);
    unsigned short* h   = (unsigned short*)(ws + OFF_H);
    float* hm_s   = ws + OFF_HM;
    float* hv_s   = ws + OFF_HV;
    float* zs     = ws + OFF_ZS;
    float* zs_s   = ws + OFF_ZSS;
    float* klp    = ws + OFF_KLP;
    float* msep   = ws + OFF_MSEP;
    float* accums = ws + OFF_ACC;
    unsigned short* gsb = (unsigned short*)(ws + OFF_GSB);

    bool big = ws_size >= WS_NEED_BIG;

    k_deg<<<ROWS / 4, 256, 0, stream>>>(gs, rdeg, accums, big ? gsb : nullptr);
    k_hw<<<ROWS / 16, 256, 0, stream>>>(hs, W_s, rdeg, hwT);
    if (big) {
        k_gemm_h<true><<<dim3(4, BB), 512, 0, stream>>>(gs, gsb, hwT, b_s, W_mu, W_lv,
                                                        rdeg, h, hm_s, hv_s);
        k_muflow<true><<<ROWS / 16, 256, 0, stream>>>(gs, gsb, hm_s, hv_s, eps, b_mu, b_lv,
                                                      beta, fw, fb, fs, rdeg, zs, zs_s, klp);
        k_dec<true><<<ROWS / 16, 256, 0, stream>>>(gs, gsb, zs_s, h, W_dec, b_dec, msep);
    } else {
        k_gemm_h<false><<<dim3(4, BB), 512, 0, stream>>>(gs, gsb, hwT, b_s, W_mu, W_lv,
                                                         rdeg, h, hm_s, hv_s);
        k_muflow<false><<<ROWS / 16, 256, 0, stream>>>(gs, gsb, hm_s, hv_s, eps, b_mu, b_lv,
                                                       beta, fw, fb, fs, rdeg, zs, zs_s, klp);
        k_dec<false><<<ROWS / 16, 256, 0, stream>>>(gs, gsb, zs_s, h, W_dec, b_dec, msep);
    }
    k_hg_cls<<<BB, 256, 0, stream>>>(h, zs, W1, b1, W2, b2, labels, klp, msep,
                                     accums, (float*)d_out);
}

// Round 6
// 116.817 us; speedup vs baseline: 4.7711x; 1.3189x over previous
//
#include <hip/hip_runtime.h>
#include <hip/hip_bf16.h>

#define BB 128
#define NN 512
#define IND 128
#define LD 64
#define NC 10
#define FL 4
#define ROWS (BB*NN)          // 65536

// workspace layout (float units)
#define OFF_ACC 0             // 8: [kl, mse, nll, acc, counter, pad...]
#define OFF_GSB 8             // gs bf16 [ROWS][512] = ROWS*256 floats
#define WS_NEED ((size_t)(OFF_GSB + (size_t)ROWS*256) * 4)

typedef __attribute__((ext_vector_type(8))) short short8v;
typedef __attribute__((ext_vector_type(4))) float f32x4;

__device__ inline float wave_reduce(float v) {
    #pragma unroll
    for (int m = 32; m; m >>= 1) v += __shfl_xor(v, m, 64);
    return v;
}

__device__ inline short f2bf(float f) {
    unsigned u = __float_as_uint(f);
    u += 0x7fff + ((u >> 16) & 1);      // round-to-nearest-even
    return (short)(u >> 16);
}

__device__ inline float bf2f(short s) {
    return __uint_as_float(((unsigned)(unsigned short)s) << 16);
}

__global__ void k_zero(float* __restrict__ accums) {
    if (threadIdx.x < 8) accums[threadIdx.x] = 0.f;
}

// One block per batch sample. 1024 threads = 16 waves.
// Phases: A deg+gsb | B1 W_s^T->LDS | B2 hw=rdeg*(hs@W_s) MFMA | C h=relu(g@hw+b_s) MFMA
//         D1 hm/hv | D2a mu/lv matvec | D2b flow | E dec matvec+mse | F hg+classifier.
template<bool BF>
__global__ __launch_bounds__(1024) void k_fused(
    const float* __restrict__ gs, const float* __restrict__ hs,
    const int* __restrict__ labels, const float* __restrict__ eps,
    const float* __restrict__ W_s, const float* __restrict__ b_s,
    const float* __restrict__ W_mu, const float* __restrict__ b_mu,
    const float* __restrict__ W_lv, const float* __restrict__ b_lv,
    const float* __restrict__ W_dec, const float* __restrict__ b_dec,
    const float* __restrict__ W1, const float* __restrict__ b1,
    const float* __restrict__ W2, const float* __restrict__ b2,
    const float* __restrict__ beta, const float* __restrict__ fw,
    const float* __restrict__ fb, const float* __restrict__ fs,
    unsigned short* __restrict__ gsb,
    float* __restrict__ accums, float* __restrict__ out)
{
    __shared__ unsigned short s_hwT[64 * 512];   // 64 KB, [l][n] bf16, XOR-swizzled
    __shared__ unsigned short s_h[512 * 64];     // 64 KB, [n][l] bf16 (aliased as sWT in B)
    __shared__ float s_rdeg[NN];                 // 2 KB
    __shared__ float s_vm[NN], s_vv[NN];         // 4 KB
    __shared__ float s_zs[NN], s_zss[NN];        // 4 KB
    __shared__ float s_red[16 * 68];             // 4.25 KB
    __shared__ float s_fin[48];

    const int tid = threadIdx.x, lane = tid & 63, wid = tid >> 6;
    const int b = blockIdx.x;

    // ---------- phase A: row sums -> rdeg; bf16 copy of gs ----------
    for (int r = 0; r < 32; ++r) {
        int row = wid * 32 + r;
        const float4* gp = (const float4*)(gs + ((size_t)b * NN + row) * NN) + lane * 2;
        float4 a = gp[0], c = gp[1];
        float ssum = a.x + a.y + a.z + a.w + c.x + c.y + c.z + c.w;
        ssum = wave_reduce(ssum);
        if (lane == 0) s_rdeg[row] = 1.f / ssum;
        if constexpr (BF) {
            short8v v;
            v[0] = f2bf(a.x); v[1] = f2bf(a.y); v[2] = f2bf(a.z); v[3] = f2bf(a.w);
            v[4] = f2bf(c.x); v[5] = f2bf(c.y); v[6] = f2bf(c.z); v[7] = f2bf(c.w);
            *(short8v*)(gsb + ((size_t)b * NN + row) * NN + lane * 8) = v;
        }
    }

    // ---------- phase B1: W_s^T (bf16, swizzled) into sWT (= s_h alias) ----------
    unsigned short* sWT = s_h;   // 64x128 bf16 = 16 KB
    {
        const float4* wp = (const float4*)W_s + tid * 2;
        float4 w0 = wp[0], w1 = wp[1];
        int k = tid >> 3, l0 = (tid & 7) * 8;
        float wv[8] = {w0.x, w0.y, w0.z, w0.w, w1.x, w1.y, w1.z, w1.w};
        #pragma unroll
        for (int e = 0; e < 8; ++e) {
            int l = l0 + e;
            int byte = (l * 256 + k * 2) ^ ((l & 7) << 4);
            *(unsigned short*)((char*)sWT + byte) = (unsigned short)f2bf(wv[e]);
        }
    }
    __syncthreads();   // rdeg + sWT ready

    // ---------- phase B2: hwT[l][n] = bf16(rdeg[n]*(hs@W_s)[n][l]) via MFMA ----------
    {
        int n0 = wid * 32, cq = lane & 15, koq = lane >> 4;
        f32x4 accB[2][4] = {};
        #pragma unroll
        for (int kk = 0; kk < 4; ++kk) {
            short8v bf[4];
            #pragma unroll
            for (int lt = 0; lt < 4; ++lt) {
                int l = lt * 16 + cq;
                int byte = (l * 256 + (kk * 32 + koq * 8) * 2) ^ ((l & 7) << 4);
                bf[lt] = *(const short8v*)((char*)sWT + byte);
            }
            #pragma unroll
            for (int nt = 0; nt < 2; ++nt) {
                int row = n0 + nt * 16 + cq;
                const float4* hp = (const float4*)(hs + ((size_t)b * NN + row) * IND
                                                   + kk * 32 + koq * 8);
                float4 h0 = hp[0], h1 = hp[1];
                short8v a;
                a[0] = f2bf(h0.x); a[1] = f2bf(h0.y); a[2] = f2bf(h0.z); a[3] = f2bf(h0.w);
                a[4] = f2bf(h1.x); a[5] = f2bf(h1.y); a[6] = f2bf(h1.z); a[7] = f2bf(h1.w);
                #pragma unroll
                for (int lt = 0; lt < 4; ++lt)
                    accB[nt][lt] = __builtin_amdgcn_mfma_f32_16x16x32_bf16(a, bf[lt], accB[nt][lt], 0, 0, 0);
            }
        }
        int r0 = (lane >> 4) * 4;
        #pragma unroll
        for (int nt = 0; nt < 2; ++nt)
            #pragma unroll
            for (int lt = 0; lt < 4; ++lt)
                #pragma unroll
                for (int q = 0; q < 4; ++q) {
                    int n = n0 + nt * 16 + r0 + q;
                    int l = lt * 16 + cq;
                    int byte = (l * 1024 + n * 2) ^ ((l & 7) << 4);
                    *(unsigned short*)((char*)s_hwT + byte) =
                        (unsigned short)f2bf(accB[nt][lt][q] * s_rdeg[n]);
                }
    }
    __syncthreads();   // hwT ready; sWT dead

    // ---------- phase C: h = relu(g @ hw + b_s) via MFMA ----------
    {
        int n0 = wid * 32, cq = lane & 15, koq = lane >> 4;
        f32x4 accC[2][4] = {};
        for (int kk = 0; kk < 16; ++kk) {
            short8v bf[4];
            #pragma unroll
            for (int lt = 0; lt < 4; ++lt) {
                int l = lt * 16 + cq;
                int byte = (l * 1024 + (kk * 32 + koq * 8) * 2) ^ ((l & 7) << 4);
                bf[lt] = *(const short8v*)((char*)s_hwT + byte);
            }
            #pragma unroll
            for (int nt = 0; nt < 2; ++nt) {
                int row = n0 + nt * 16 + cq;
                short8v a;
                if constexpr (BF) {
                    a = *(const short8v*)(gsb + ((size_t)b * NN + row) * NN + kk * 32 + koq * 8);
                } else {
                    const float4* gp = (const float4*)(gs + ((size_t)b * NN + row) * NN
                                                       + kk * 32 + koq * 8);
                    float4 g0 = gp[0], g1 = gp[1];
                    a[0] = f2bf(g0.x); a[1] = f2bf(g0.y); a[2] = f2bf(g0.z); a[3] = f2bf(g0.w);
                    a[4] = f2bf(g1.x); a[5] = f2bf(g1.y); a[6] = f2bf(g1.z); a[7] = f2bf(g1.w);
                }
                #pragma unroll
                for (int lt = 0; lt < 4; ++lt)
                    accC[nt][lt] = __builtin_amdgcn_mfma_f32_16x16x32_bf16(a, bf[lt], accC[nt][lt], 0, 0, 0);
            }
        }
        int r0 = (lane >> 4) * 4;
        float bsv[4];
        #pragma unroll
        for (int lt = 0; lt < 4; ++lt) bsv[lt] = b_s[lt * 16 + cq];
        #pragma unroll
        for (int nt = 0; nt < 2; ++nt)
            #pragma unroll
            for (int lt = 0; lt < 4; ++lt)
                #pragma unroll
                for (int q = 0; q < 4; ++q) {
                    int n = n0 + nt * 16 + r0 + q;
                    int l = lt * 16 + cq;
                    s_h[n * 64 + l] = (unsigned short)f2bf(fmaxf(accC[nt][lt][q] + bsv[lt], 0.f));
                }
    }
    __syncthreads();   // h ready

    // ---------- phase D1: hm_s/hv_s[j] = rdeg[j] * (h[j]@W_mu / @W_lv) ----------
    {
        int g16 = tid >> 4, l16 = tid & 15;
        float wmu[4], wlv[4];
        #pragma unroll
        for (int e = 0; e < 4; ++e) { wmu[e] = W_mu[l16 * 4 + e]; wlv[e] = W_lv[l16 * 4 + e]; }
        #pragma unroll
        for (int rr = 0; rr < 8; ++rr) {
            int row = g16 * 8 + rr;
            const unsigned short* hp = &s_h[row * 64 + l16 * 4];
            float pm = 0.f, pv = 0.f;
            #pragma unroll
            for (int e = 0; e < 4; ++e) {
                float hv = bf2f((short)hp[e]);
                pm += hv * wmu[e]; pv += hv * wlv[e];
            }
            #pragma unroll
            for (int m = 1; m <= 8; m <<= 1) {
                pm += __shfl_xor(pm, m, 64);
                pv += __shfl_xor(pv, m, 64);
            }
            if (l16 == 0) {
                float rd = s_rdeg[row];
                s_vm[row] = pm * rd;
                s_vv[row] = pv * rd;
            }
        }
    }
    __syncthreads();

    // ---------- phase D2a: mu_pre/lv_pre[i] = g[i,:] . hm_s / hv_s ----------
    {
        float vmr[8], vvr[8];
        #pragma unroll
        for (int e = 0; e < 8; ++e) { vmr[e] = s_vm[lane * 8 + e]; vvr[e] = s_vv[lane * 8 + e]; }
        for (int r = 0; r < 32; ++r) {
            int row = wid * 32 + r;
            float sm, sv;
            if constexpr (BF) {
                short8v g8 = *(const short8v*)(gsb + ((size_t)b * NN + row) * NN + lane * 8);
                float g0 = bf2f(g8[0]), g1 = bf2f(g8[1]), g2 = bf2f(g8[2]), g3 = bf2f(g8[3]);
                float g4 = bf2f(g8[4]), g5 = bf2f(g8[5]), g6 = bf2f(g8[6]), g7 = bf2f(g8[7]);
                sm = g0*vmr[0]+g1*vmr[1]+g2*vmr[2]+g3*vmr[3]+g4*vmr[4]+g5*vmr[5]+g6*vmr[6]+g7*vmr[7];
                sv = g0*vvr[0]+g1*vvr[1]+g2*vvr[2]+g3*vvr[3]+g4*vvr[4]+g5*vvr[5]+g6*vvr[6]+g7*vvr[7];
            } else {
                const float4* gp = (const float4*)(gs + ((size_t)b * NN + row) * NN) + lane * 2;
                float4 ga = gp[0], gc = gp[1];
                sm = ga.x*vmr[0]+ga.y*vmr[1]+ga.z*vmr[2]+ga.w*vmr[3]
                   + gc.x*vmr[4]+gc.y*vmr[5]+gc.z*vmr[6]+gc.w*vmr[7];
                sv = ga.x*vvr[0]+ga.y*vvr[1]+ga.z*vvr[2]+ga.w*vvr[3]
                   + gc.x*vvr[4]+gc.y*vvr[5]+gc.z*vvr[6]+gc.w*vvr[7];
            }
            sm = wave_reduce(sm);
            sv = wave_reduce(sv);
            if (lane == 0) { s_zs[row] = sm; s_zss[row] = sv; }   // mu_pre / lv_pre
        }
    }
    __syncthreads();

    // ---------- phase D2b: flow epilogue, 512 threads lane-parallel ----------
    float my_kl = 0.f;
    if (tid < NN) {
        float sm = s_zs[tid], sv = s_zss[tid];
        float mu = fmaxf(sm + b_mu[0], 0.f);
        float lv = fmaxf(sv + b_lv[0], 0.f);
        float sigma = expf(0.5f * lv);
        float z0 = eps[(size_t)b * NN + tid] * sigma + mu;
        float z = z0, lj = 0.f;
        #pragma unroll
        for (int k = 0; k < FL; ++k) {
            float tt = tanhf(fw[k] * z + fb[k]);
            float det = 1.f + fs[k] * fw[k] * (1.f - tt * tt);
            lj += logf(fabsf(det) + 1e-7f);
            z += fs[k] * tt;
        }
        float e0 = (z0 - mu) / sigma;
        float logq = -0.5f * e0 * e0 - logf(2.5f * sigma);
        float logp = -0.5f * z * z - logf(2.5f);
        my_kl = logq - lj - logp;
        float zv = 1.f / (1.f + expf(-beta[0] * z));
        s_zs[tid] = zv;
        s_zss[tid] = zv * s_rdeg[tid];
    }
    __syncthreads();

    // ---------- phase E: d_pre matvec + mse ----------
    float msacc = 0.f;
    {
        float wd = W_dec[lane], bd = b_dec[lane];
        float zr[8];
        #pragma unroll
        for (int e = 0; e < 8; ++e) zr[e] = s_zss[lane * 8 + e];
        for (int r = 0; r < 32; ++r) {
            int row = wid * 32 + r;
            float s;
            if constexpr (BF) {
                short8v g8 = *(const short8v*)(gsb + ((size_t)b * NN + row) * NN + lane * 8);
                s = bf2f(g8[0])*zr[0]+bf2f(g8[1])*zr[1]+bf2f(g8[2])*zr[2]+bf2f(g8[3])*zr[3]
                  + bf2f(g8[4])*zr[4]+bf2f(g8[5])*zr[5]+bf2f(g8[6])*zr[6]+bf2f(g8[7])*zr[7];
            } else {
                const float4* gp = (const float4*)(gs + ((size_t)b * NN + row) * NN) + lane * 2;
                float4 ga = gp[0], gc = gp[1];
                s = ga.x*zr[0]+ga.y*zr[1]+ga.z*zr[2]+ga.w*zr[3]
                  + gc.x*zr[4]+gc.y*zr[5]+gc.z*zr[6]+gc.w*zr[7];
            }
            s = wave_reduce(s);
            float dval = fmaxf(s * wd + bd, 0.f);
            float diff = bf2f((short)s_h[row * 64 + lane]) - dval;
            msacc += diff * diff;
        }
    }

    // ---------- phase F: hg partials ----------
    {
        float acc = 0.f;
        for (int r = 0; r < 32; ++r) {
            int row = wid * 32 + r;
            acc += bf2f((short)s_h[row * 64 + lane]) * s_zs[row];
        }
        s_red[wid * 68 + lane] = acc;
    }
    __syncthreads();

    // kl / mse partials per wave
    {
        float kv = wave_reduce(my_kl);
        float mv = wave_reduce(msacc);
        if (lane == 0) { s_fin[wid] = kv; s_fin[16 + wid] = mv; }
    }
    // classifier on wave 0
    if (wid == 0) {
        float hgv = 0.f;
        #pragma unroll
        for (int w = 0; w < 16; ++w) hgv += s_red[w * 68 + lane];
        s_red[lane] = hgv;
        float x = b1[lane];
        #pragma unroll 8
        for (int k = 0; k < LD; ++k) x += s_red[k] * W1[k * LD + lane];
        x = fmaxf(x, 0.f);
        s_red[256 + lane] = x;
        if (lane < NC) {
            float lg = b2[lane];
            #pragma unroll 8
            for (int k = 0; k < LD; ++k) lg += s_red[256 + k] * W2[k * NC + lane];
            s_fin[32 + lane] = lg;
        }
        if (lane == 0) {
            float mx = s_fin[32]; int pred = 0;
            #pragma unroll
            for (int c = 1; c < NC; ++c) if (s_fin[32 + c] > mx) { mx = s_fin[32 + c]; pred = c; }
            float se = 0.f;
            #pragma unroll
            for (int c = 0; c < NC; ++c) se += expf(s_fin[32 + c] - mx);
            int lab = labels[b];
            s_fin[44] = -(s_fin[32 + lab] - (mx + logf(se)));
            s_fin[45] = (pred == lab) ? 1.f : 0.f;
        }
    }
    __syncthreads();

    if (tid == 0) {
        float ksum = 0.f, msum = 0.f;
        #pragma unroll
        for (int w = 0; w < 16; ++w) { ksum += s_fin[w]; msum += s_fin[16 + w]; }
        atomicAdd(&accums[0], ksum);
        atomicAdd(&accums[1], msum);
        atomicAdd(&accums[2], s_fin[44]);
        atomicAdd(&accums[3], s_fin[45]);
        __threadfence();
        unsigned old = atomicAdd((unsigned*)&accums[4], 1u);
        if (old == BB - 1) {
            float kk = atomicAdd(&accums[0], 0.f);
            float mm = atomicAdd(&accums[1], 0.f);
            float nn = atomicAdd(&accums[2], 0.f);
            float aa = atomicAdd(&accums[3], 0.f);
            out[0] = nn / (float)BB
                   + mm / ((float)BB * NN * LD)
                   + kk / ((float)BB * NN);
            out[1] = aa / (float)BB;
        }
    }
}

extern "C" void kernel_launch(void* const* d_in, const int* in_sizes, int n_in,
                              void* d_out, int out_size, void* d_ws, size_t ws_size,
                              hipStream_t stream) {
    const float* gs    = (const float*)d_in[0];
    const float* hs    = (const float*)d_in[1];
    const int*   labels= (const int*)d_in[2];
    const float* eps   = (const float*)d_in[3];
    const float* W_s   = (const float*)d_in[4];
    const float* b_s   = (const float*)d_in[5];
    const float* W_mu  = (const float*)d_in[6];
    const float* b_mu  = (const float*)d_in[7];
    const float* W_lv  = (const float*)d_in[8];
    const float* b_lv  = (const float*)d_in[9];
    const float* W_dec = (const float*)d_in[10];
    const float* b_dec = (const float*)d_in[11];
    const float* W1    = (const float*)d_in[12];
    const float* b1    = (const float*)d_in[13];
    const float* W2    = (const float*)d_in[14];
    const float* b2    = (const float*)d_in[15];
    const float* beta  = (const float*)d_in[16];
    const float* fw    = (const float*)d_in[17];
    const float* fb    = (const float*)d_in[18];
    const float* fs    = (const float*)d_in[19];

    float* ws = (float*)d_ws;
    float* accums = ws + OFF_ACC;
    unsigned short* gsb = (unsigned short*)(ws + OFF_GSB);
    float* out = (float*)d_out;

    k_zero<<<1, 64, 0, stream>>>(accums);
    if (ws_size >= WS_NEED) {
        k_fused<true><<<BB, 1024, 0, stream>>>(gs, hs, labels, eps, W_s, b_s, W_mu, b_mu,
                                               W_lv, b_lv, W_dec, b_dec, W1, b1, W2, b2,
                                               beta, fw, fb, fs, gsb, accums, out);
    } else {
        k_fused<false><<<BB, 1024, 0, stream>>>(gs, hs, labels, eps, W_s, b_s, W_mu, b_mu,
                                                W_lv, b_lv, W_dec, b_dec, W1, b1, W2, b2,
                                                beta, fw, fb, fs, gsb, accums, out);
    }
}